// Round 6
// baseline (119.744 us; speedup 1.0000x reference)
//
#include <hip/hip_runtime.h>

typedef __attribute__((ext_vector_type(4))) float f32x4;
typedef __attribute__((ext_vector_type(8))) short bf16x8;
typedef __attribute__((ext_vector_type(4))) unsigned int u32x4;

#define IDIM    128
#define HID     64
#define TDEPTH  6
#define MTILE   64
#define NWAVES  6
#define BLOCK   (NWAVES * 64)
#define WFRAG_ELEMS (6 * 4 * 4 * 512)   // nd, ks, ct, lane*8+j

__device__ __forceinline__ unsigned short f2bf(float f) {
    unsigned int u = __builtin_bit_cast(unsigned int, f);
    unsigned int r = (u + 0x7FFFu + ((u >> 16) & 1u)) >> 16;  // RNE
    return (unsigned short)r;
}

// Pack two fp32 -> one u32 of 2 bf16 (RNE)
__device__ __forceinline__ unsigned int f2bf_pk(float f0, float f1) {
    unsigned int u0 = __builtin_bit_cast(unsigned int, f0);
    unsigned int u1 = __builtin_bit_cast(unsigned int, f1);
    unsigned int t0 = u0 + 0x7FFFu + ((u0 >> 16) & 1u);
    unsigned int t1 = u1 + 0x7FFFu + ((u1 >> 16) & 1u);
    return (t1 & 0xFFFF0000u) | (t0 >> 16);
}

// Pre-convert W1 (6 chain nodes) into bf16 MFMA B-fragment layout.
// B-frag: lane holds B[k=(lane>>4)*8+j][n=lane&15]. Workspace use is free
// (the harness's 268 MB poison fill runs unconditionally — round-3/5 finding;
// it also evicts L3 every iteration, so x is always HBM-cold).
__global__ void prep_wfrag(const float* __restrict__ W1, unsigned short* __restrict__ wfrag) {
    int idx = blockIdx.x * 256 + threadIdx.x;
    if (idx >= WFRAG_ELEMS) return;
    int j    = idx & 7;
    int lane = (idx >> 3) & 63;
    int ct   = (idx >> 9) & 3;
    int ks   = (idx >> 11) & 3;
    int nd   = idx >> 13;
    int node = (1 << nd) - 1;              // chain node: 0,1,3,7,15,31
    int k    = ks * 32 + (lane >> 4) * 8 + j;
    int col  = ct * 16 + (lane & 15);
    wfrag[idx] = f2bf(W1[(node * IDIM + k) * HID + col]);
}

// Session model (rounds 2/4/5 all ~45us at 780 GB/s = 12% BW, independent of
// spill state): the LDS-staged x path is HBM-LATENCY-bound — barriers leave
// only short windows with loads outstanding. Fix: build the MFMA A-fragment
// DIRECTLY from global x (lane reads 8 contiguous floats; per (rt,ks) the wave
// covers 16 full 128B cachelines). 6 waves re-read the same rows (L1/L2
// absorbs; HBM stays 33.5 MB) but the block has NO staging phase and ONE
// barrier total -> loads in flight from cycle 0 across 12 waves/CU.
// B-frags stream from wfrag inside the (fully unrolled) ks loop; no outer
// t loop remains, so LICM cannot recreate round-4/5's 64-reg resident set.
template <bool USE_WS>
__global__ __launch_bounds__(BLOCK, 3)
void sdt_kernel(const float* __restrict__ x, const float* __restrict__ W1,
                const float* __restrict__ b1, const float* __restrict__ W2,
                const float* __restrict__ b2, const float* __restrict__ leaf,
                const unsigned short* __restrict__ wfrag, float* __restrict__ out) {
    __shared__ float p_lds[TDEPTH][MTILE];
    __shared__ float leaf_lds[64];

    const int tid    = threadIdx.x;
    const int m_base = blockIdx.x * MTILE;

    const int wave = tid >> 6;
    const int lane = tid & 63;
    const int node = (1 << wave) - 1;                // 0,1,3,7,15,31
    const int lcol = lane & 15;
    const int lq   = lane >> 4;

    if (tid < 64) leaf_lds[tid] = leaf[tid];

    // epilogue params (latency hides under the GEMM loads)
    float b1v[4], w2v[4];
    #pragma unroll
    for (int ct = 0; ct < 4; ct++) {
        int col = ct * 16 + lcol;
        b1v[ct] = b1[node * HID + col];
        w2v[ct] = W2[node * HID + col];
    }
    const float bias2 = b2[node];

    // ---- GEMM: 64 rows x 64 cols per wave, K=128, A-frags straight from HBM ----
    // A-frag: lane holds A[row = rt*16 + lcol][k = ks*32 + lq*8 + j]
    const float* xbase = x + (size_t)(m_base + lcol) * IDIM + lq * 8;

    f32x4 acc[4][4];
    #pragma unroll
    for (int rt = 0; rt < 4; rt++)
        #pragma unroll
        for (int ct = 0; ct < 4; ct++)
            acc[rt][ct] = (f32x4){0.f, 0.f, 0.f, 0.f};

    #pragma unroll
    for (int ks = 0; ks < 4; ks++) {
        bf16x8 bfrag[4];
        if (USE_WS) {
            #pragma unroll
            for (int ct = 0; ct < 4; ct++)
                bfrag[ct] = *reinterpret_cast<const bf16x8*>(
                    wfrag + (((wave * 4 + ks) * 4 + ct) * 512 + lane * 8));
        } else {
            const float* wsrc = W1 + (size_t)node * IDIM * HID + lcol;
            const int k0 = ks * 32 + lq * 8;
            #pragma unroll
            for (int ct = 0; ct < 4; ct++) {
                const float* wc = wsrc + (size_t)k0 * HID + ct * 16;
                u32x4 pk;
                #pragma unroll
                for (int jp = 0; jp < 4; jp++)
                    pk[jp] = f2bf_pk(wc[(2 * jp) * HID], wc[(2 * jp + 1) * HID]);
                bfrag[ct] = __builtin_bit_cast(bf16x8, pk);
            }
        }
        #pragma unroll
        for (int rt = 0; rt < 4; rt++) {
            const float4* a4 = reinterpret_cast<const float4*>(
                xbase + (size_t)(rt * 16) * IDIM + ks * 32);
            float4 v0 = a4[0];
            float4 v1 = a4[1];
            u32x4 pk;
            pk[0] = f2bf_pk(v0.x, v0.y);
            pk[1] = f2bf_pk(v0.z, v0.w);
            pk[2] = f2bf_pk(v1.x, v1.y);
            pk[3] = f2bf_pk(v1.z, v1.w);
            bf16x8 afrag = __builtin_bit_cast(bf16x8, pk);
            #pragma unroll
            for (int ct = 0; ct < 4; ct++)
                acc[rt][ct] = __builtin_amdgcn_mfma_f32_16x16x32_bf16(
                    afrag, bfrag[ct], acc[rt][ct], 0, 0, 0);
        }
    }

    // ---- epilogue: relu, dot W2, sigmoid -> p_lds ----
    // C layout: col = ct*16 + lcol, row = rt*16 + lq*4 + r
    #pragma unroll
    for (int rt = 0; rt < 4; rt++) {
        #pragma unroll
        for (int r = 0; r < 4; r++) {
            float s = 0.f;
            #pragma unroll
            for (int ct = 0; ct < 4; ct++) {
                float v = acc[rt][ct][r] + b1v[ct];
                v = v > 0.f ? v : 0.f;
                s += v * w2v[ct];
            }
            #pragma unroll
            for (int d = 1; d < 16; d <<= 1)
                s += __shfl_xor(s, d, 64);
            float p = 1.f / (1.f + __expf(-(s + bias2)));
            if (lcol == 0)
                p_lds[wave][rt * 16 + lq * 4 + r] = p;
        }
    }
    __syncthreads();   // the block's ONLY barrier

    // ---- fold by wave 0: out[row] = sum_ch f4*f5*DP16(leaf_chunk, q0..q3) ----
    if (wave == 0) {
        const int row = lane;
        float q0 = p_lds[0][row];
        float q1 = p_lds[1][row];
        float q2 = p_lds[2][row];
        float q3 = p_lds[3][row];
        float p4 = p_lds[4][row];
        float p5 = p_lds[5][row];
        float acc_out = 0.f;
        #pragma unroll
        for (int ch = 0; ch < 4; ch++) {
            float f4 = (ch & 1) ? p4 : 1.f - p4;
            float f5 = (ch & 2) ? p5 : 1.f - p5;
            const float* lf = leaf_lds + ch * 16;
            float tt[8];
            #pragma unroll
            for (int j = 0; j < 8; j++) {
                float a = lf[2 * j], b = lf[2 * j + 1];
                tt[j] = a + q0 * (b - a);
            }
            #pragma unroll
            for (int j = 0; j < 4; j++) tt[j] = tt[2 * j] + q1 * (tt[2 * j + 1] - tt[2 * j]);
            #pragma unroll
            for (int j = 0; j < 2; j++) tt[j] = tt[2 * j] + q2 * (tt[2 * j + 1] - tt[2 * j]);
            float s = tt[0] + q3 * (tt[1] - tt[0]);
            acc_out += f4 * f5 * s;
        }
        out[(size_t)m_base + row] = acc_out;
    }
}

extern "C" void kernel_launch(void* const* d_in, const int* in_sizes, int n_in,
                              void* d_out, int out_size, void* d_ws, size_t ws_size,
                              hipStream_t stream) {
    const float* x    = (const float*)d_in[0];
    const float* W1   = (const float*)d_in[1];
    const float* b1   = (const float*)d_in[2];
    const float* W2   = (const float*)d_in[3];
    const float* b2   = (const float*)d_in[4];
    const float* leaf = (const float*)d_in[5];
    float* out = (float*)d_out;

    const int Bn = in_sizes[0] / IDIM;               // 65536
    const int nblocks = Bn / MTILE;                  // 1024

    if (ws_size >= (size_t)WFRAG_ELEMS * sizeof(unsigned short)) {
        unsigned short* wfrag = (unsigned short*)d_ws;
        prep_wfrag<<<(WFRAG_ELEMS + 255) / 256, 256, 0, stream>>>(W1, wfrag);
        sdt_kernel<true><<<nblocks, BLOCK, 0, stream>>>(x, W1, b1, W2, b2, leaf, wfrag, out);
    } else {
        sdt_kernel<false><<<nblocks, BLOCK, 0, stream>>>(x, W1, b1, W2, b2, leaf, nullptr, out);
    }
}

// Round 7
// 99.393 us; speedup vs baseline: 1.2047x; 1.2047x over previous
//
#include <hip/hip_runtime.h>

typedef __attribute__((ext_vector_type(4))) float f32x4;
typedef __attribute__((ext_vector_type(8))) short bf16x8;
typedef __attribute__((ext_vector_type(4))) unsigned int u32x4;

#define IDIM    128
#define HID     64
#define TDEPTH  6
#define WROWS   32                       // rows per wave
#define NWAVES  4
#define BLOCK   (NWAVES * 64)            // 256
#define MROWS   (WROWS * NWAVES)         // 128 rows per block
#define NODE_ELEMS 8192                  // shorts per node B-fragment slice (16 KB)
#define WFRAG_ELEMS (TDEPTH * NODE_ELEMS)

__device__ __forceinline__ unsigned short f2bf(float f) {
    unsigned int u = __builtin_bit_cast(unsigned int, f);
    unsigned int r = (u + 0x7FFFu + ((u >> 16) & 1u)) >> 16;  // RNE
    return (unsigned short)r;
}

__device__ __forceinline__ unsigned int f2bf_pk(float f0, float f1) {
    unsigned int u0 = __builtin_bit_cast(unsigned int, f0);
    unsigned int u1 = __builtin_bit_cast(unsigned int, f1);
    unsigned int t0 = u0 + 0x7FFFu + ((u0 >> 16) & 1u);
    unsigned int t1 = u1 + 0x7FFFu + ((u1 >> 16) & 1u);
    return (t1 & 0xFFFF0000u) | (t0 >> 16);
}

// Pre-convert W1 (6 chain nodes) into bf16 MFMA B-fragment layout, node-major.
// B-frag: lane holds B[k=(lane>>4)*8+j][n=lane&15]. Workspace use is free
// (the harness's 268 MB poison fill runs unconditionally; it also evicts L3,
// so x is HBM-cold every iteration).
__global__ void prep_wfrag(const float* __restrict__ W1, unsigned short* __restrict__ wfrag) {
    int idx = blockIdx.x * 256 + threadIdx.x;
    if (idx >= WFRAG_ELEMS) return;
    int j    = idx & 7;
    int lane = (idx >> 3) & 63;
    int ct   = (idx >> 9) & 3;
    int ks   = (idx >> 11) & 3;
    int nd   = idx >> 13;
    int node = (1 << nd) - 1;              // chain node: 0,1,3,7,15,31
    int k    = ks * 32 + (lane >> 4) * 8 + j;
    int col  = ct * 16 + (lane & 15);
    wfrag[idx] = f2bf(W1[(node * IDIM + k) * HID + col]);
}

// Round-7 structure (session model: rounds 2-6 all latency-bound, 345-790 GB/s,
// floor is ~5.3us x-stream + ~2.4us VALU):
//   wave = 32 rows x ALL 6 nodes. A loaded ONCE per wave (16 dwordx4 burst,
//   held in 32 VGPRs) -> zero A re-read, whole x stream in flight from cycle 0.
//   B staged per node into LDS (double-buffered 2x16KB) by the whole block ->
//   B L2 traffic 49 MB total. Entire grid resident (512 blocks, 8 waves/CU of
//   work < 12 capacity at launch_bounds(256,3)) -> no dispatch tail; barriers
//   only in the compute-dense post-burst region.
template <bool USE_WS>
__global__ __launch_bounds__(BLOCK, 3)
void sdt_kernel(const float* __restrict__ x, const float* __restrict__ W1,
                const float* __restrict__ b1, const float* __restrict__ W2,
                const float* __restrict__ b2, const float* __restrict__ leaf,
                const unsigned short* __restrict__ wfrag, float* __restrict__ out) {
    __shared__ __align__(16) unsigned short bs[2][NODE_ELEMS];  // 32 KB
    __shared__ float p_lds[NWAVES][WROWS][8];                   // [..][nd], padded
    __shared__ float leaf_lds[64];

    const int tid  = threadIdx.x;
    const int wave = tid >> 6;
    const int lane = tid & 63;
    const int lcol = lane & 15;
    const int lq   = lane >> 4;
    const int m0   = blockIdx.x * MROWS + wave * WROWS;

    // ---- A: this wave's 32 rows, straight from HBM, issued as one burst ----
    // A-frag target: lane holds A[row = rt*16 + lcol][k = ks*32 + lq*8 + j]
    const float* xb = x + (size_t)(m0 + lcol) * IDIM + lq * 8;
    float4 araw[2][4][2];
    #pragma unroll
    for (int rt = 0; rt < 2; rt++)
        #pragma unroll
        for (int ks = 0; ks < 4; ks++) {
            const float4* ap = reinterpret_cast<const float4*>(
                xb + (size_t)(rt * 16) * IDIM + ks * 32);
            araw[rt][ks][0] = ap[0];
            araw[rt][ks][1] = ap[1];
        }

    // ---- stage node-0 B fragment + leaf while A loads are in flight ----
    auto stage = [&](int buf, int nd) {
        if (USE_WS) {
            const u32x4* src = reinterpret_cast<const u32x4*>(wfrag + nd * NODE_ELEMS);
            u32x4* dst = reinterpret_cast<u32x4*>(&bs[buf][0]);
            #pragma unroll
            for (int i = 0; i < (NODE_ELEMS * 2 / 16) / BLOCK; i++)   // 4
                dst[tid + i * BLOCK] = src[tid + i * BLOCK];
        } else {
            int node = (1 << nd) - 1;
            for (int e = tid; e < NODE_ELEMS; e += BLOCK) {
                int j = e & 7, ln = (e >> 3) & 63, ct = (e >> 9) & 3, ks = e >> 11;
                int k   = ks * 32 + (ln >> 4) * 8 + j;
                int col = ct * 16 + (ln & 15);
                bs[buf][e] = f2bf(W1[((size_t)node * IDIM + k) * HID + col]);
            }
        }
    };
    stage(0, 0);
    if (tid < 64) leaf_lds[tid] = leaf[tid];

    // ---- convert A to bf16 fragments (held for all 6 nodes) ----
    bf16x8 afrag[2][4];
    #pragma unroll
    for (int rt = 0; rt < 2; rt++)
        #pragma unroll
        for (int ks = 0; ks < 4; ks++) {
            float4 v0 = araw[rt][ks][0], v1 = araw[rt][ks][1];
            u32x4 pk;
            pk[0] = f2bf_pk(v0.x, v0.y);
            pk[1] = f2bf_pk(v0.z, v0.w);
            pk[2] = f2bf_pk(v1.x, v1.y);
            pk[3] = f2bf_pk(v1.z, v1.w);
            afrag[rt][ks] = __builtin_bit_cast(bf16x8, pk);
        }

    __syncthreads();                        // bs[0] + leaf ready

    #pragma unroll
    for (int nd = 0; nd < TDEPTH; nd++) {
        const int buf = nd & 1;
        if (nd + 1 < TDEPTH) stage(buf ^ 1, nd + 1);   // prefetch next node's B

        const int node = (1 << nd) - 1;
        float b1v[4], w2v[4];
        #pragma unroll
        for (int ct = 0; ct < 4; ct++) {
            int col = ct * 16 + lcol;
            b1v[ct] = b1[node * HID + col];
            w2v[ct] = W2[node * HID + col];
        }
        const float bias2 = b2[node];

        // ---- GEMM: 32 rows x 64 cols, K=128; B from LDS ----
        f32x4 acc[2][4];
        #pragma unroll
        for (int rt = 0; rt < 2; rt++)
            #pragma unroll
            for (int ct = 0; ct < 4; ct++)
                acc[rt][ct] = (f32x4){0.f, 0.f, 0.f, 0.f};
        #pragma unroll
        for (int ks = 0; ks < 4; ks++) {
            bf16x8 bfrag[4];
            #pragma unroll
            for (int ct = 0; ct < 4; ct++)
                bfrag[ct] = *reinterpret_cast<const bf16x8*>(
                    &bs[buf][(ks * 4 + ct) * 512 + lane * 8]);
            #pragma unroll
            for (int rt = 0; rt < 2; rt++)
                #pragma unroll
                for (int ct = 0; ct < 4; ct++)
                    acc[rt][ct] = __builtin_amdgcn_mfma_f32_16x16x32_bf16(
                        afrag[rt][ks], bfrag[ct], acc[rt][ct], 0, 0, 0);
        }

        // ---- epilogue: relu, dot W2, sigmoid -> p_lds ----
        // C layout: col = ct*16 + lcol, row = rt*16 + lq*4 + r
        #pragma unroll
        for (int rt = 0; rt < 2; rt++) {
            #pragma unroll
            for (int r = 0; r < 4; r++) {
                float s = 0.f;
                #pragma unroll
                for (int ct = 0; ct < 4; ct++) {
                    float v = acc[rt][ct][r] + b1v[ct];
                    v = v > 0.f ? v : 0.f;
                    s += v * w2v[ct];
                }
                #pragma unroll
                for (int d = 1; d < 16; d <<= 1)
                    s += __shfl_xor(s, d, 64);
                float p = 1.f / (1.f + __expf(-(s + bias2)));
                if (lcol == 0)
                    p_lds[wave][rt * 16 + lq * 4 + r][nd] = p;
            }
        }
        __syncthreads();   // bs[buf^1] staged; p_lds(nd) done; bs[buf] free
    }

    // ---- fold: 128 threads, one per row ----
    if (tid < MROWS) {
        const int wv = tid >> 5, row = tid & 31;
        float q0 = p_lds[wv][row][0];
        float q1 = p_lds[wv][row][1];
        float q2 = p_lds[wv][row][2];
        float q3 = p_lds[wv][row][3];
        float p4 = p_lds[wv][row][4];
        float p5 = p_lds[wv][row][5];
        float acc_out = 0.f;
        #pragma unroll
        for (int ch = 0; ch < 4; ch++) {
            float f4 = (ch & 1) ? p4 : 1.f - p4;
            float f5 = (ch & 2) ? p5 : 1.f - p5;
            const float* lf = leaf_lds + ch * 16;
            float tt[8];
            #pragma unroll
            for (int j = 0; j < 8; j++) {
                float a = lf[2 * j], b = lf[2 * j + 1];
                tt[j] = a + q0 * (b - a);
            }
            #pragma unroll
            for (int j = 0; j < 4; j++) tt[j] = tt[2 * j] + q1 * (tt[2 * j + 1] - tt[2 * j]);
            #pragma unroll
            for (int j = 0; j < 2; j++) tt[j] = tt[2 * j] + q2 * (tt[2 * j + 1] - tt[2 * j]);
            float s = tt[0] + q3 * (tt[1] - tt[0]);
            acc_out += f4 * f5 * s;
        }
        out[(size_t)blockIdx.x * MROWS + tid] = acc_out;
    }
}

extern "C" void kernel_launch(void* const* d_in, const int* in_sizes, int n_in,
                              void* d_out, int out_size, void* d_ws, size_t ws_size,
                              hipStream_t stream) {
    const float* x    = (const float*)d_in[0];
    const float* W1   = (const float*)d_in[1];
    const float* b1   = (const float*)d_in[2];
    const float* W2   = (const float*)d_in[3];
    const float* b2   = (const float*)d_in[4];
    const float* leaf = (const float*)d_in[5];
    float* out = (float*)d_out;

    const int Bn = in_sizes[0] / IDIM;               // 65536 rows
    const int nblocks = Bn / MROWS;                  // 512 — entire grid resident

    if (ws_size >= (size_t)WFRAG_ELEMS * sizeof(unsigned short)) {
        unsigned short* wfrag = (unsigned short*)d_ws;
        prep_wfrag<<<(WFRAG_ELEMS + 255) / 256, 256, 0, stream>>>(W1, wfrag);
        sdt_kernel<true><<<nblocks, BLOCK, 0, stream>>>(x, W1, b1, W2, b2, leaf, wfrag, out);
    } else {
        sdt_kernel<false><<<nblocks, BLOCK, 0, stream>>>(x, W1, b1, W2, b2, leaf, nullptr, out);
    }
}